// Round 5
// baseline (1018.853 us; speedup 1.0000x reference)
//
#include <hip/hip_runtime.h>
#include <stdint.h>

typedef __attribute__((ext_vector_type(8))) short short8;   // 8 x bf16 (4 VGPR)
typedef __attribute__((ext_vector_type(4))) short short4v;
typedef __attribute__((ext_vector_type(2))) short short2v;
typedef __attribute__((ext_vector_type(4))) float f32x4;
typedef __attribute__((ext_vector_type(8))) __bf16 bf16x8;

__device__ __forceinline__ short f2bf(float f) {
  unsigned u = __builtin_bit_cast(unsigned, f);
  u = (u + 0x7FFFu + ((u >> 16) & 1u)) >> 16;   // RNE
  return (short)u;
}

__device__ __forceinline__ f32x4 mfma16(short8 a, short8 b, f32x4 c) {
  return __builtin_amdgcn_mfma_f32_16x16x32_bf16(
      __builtin_bit_cast(bf16x8, a), __builtin_bit_cast(bf16x8, b), c, 0, 0, 0);
}

// async global->LDS, 16B per lane. ldsptr must be wave-uniform; HW writes base + lane*16.
__device__ __forceinline__ void gload_lds16(const void* g, void* l) {
  __builtin_amdgcn_global_load_lds(
      (const __attribute__((address_space(1))) unsigned int*)g,
      (__attribute__((address_space(3))) unsigned int*)l, 16, 0, 0);
}

// ---------------- small data-movement kernels ----------------

__global__ void conv_bf16(const float* __restrict__ in, short* __restrict__ out, int n4) {
  int i = blockIdx.x * 256 + threadIdx.x;
  if (i >= n4) return;
  f32x4 v = ((const f32x4*)in)[i];
  short4v o;
  o[0] = f2bf(v[0]); o[1] = f2bf(v[1]); o[2] = f2bf(v[2]); o[3] = f2bf(v[3]);
  ((short4v*)out)[i] = o;
}

// out[c][r] = in[r][c]  (in: [R][C] f32, out: [C][R] bf16)
__global__ void transpose_f32_bf16(const float* __restrict__ in, short* __restrict__ out,
                                   int R, int C) {
  int o = blockIdx.x * 256 + threadIdx.x;
  if (o >= R * C) return;
  int c = o / R, r = o - c * R;
  out[o] = f2bf(in[(size_t)r * C + c]);
}

// kabsT[h][l][d] = kabs[(h*128+d)*512 + l]   (16*512*128 elems)
__global__ void trans_kabs(const short* __restrict__ in, short* __restrict__ out) {
  int o = blockIdx.x * 256 + threadIdx.x;
  int h = o >> 16, rem = o & 65535, l = rem >> 7, d = rem & 127;
  out[o] = in[((h << 7) + d) * 512 + l];
}

// vabsT[h][d][l] = vflat[l*2048 + h*128 + d]  (16*128*512 elems)
__global__ void trans_vabs(const short* __restrict__ in, short* __restrict__ out) {
  int o = blockIdx.x * 256 + threadIdx.x;
  int h = o >> 16, rem = o & 65535, d = rem >> 9, l = rem & 511;
  out[o] = in[l * 2048 + (h << 7) + d];
}

// ckvT[(b*512+l)*2048+t] = ckv[(b*2048+t)*512+l]
// LDS-tiled 64x64 transpose: coalesced reads AND writes.
// grid (32, 8, 2) = (t-tile, l-tile, b); 256 threads.
__global__ __launch_bounds__(256) void trans_ckvT(const short* __restrict__ in,
                                                  short* __restrict__ out) {
  __shared__ short tile[64][66];
  const int t0 = blockIdx.x * 64, l0 = blockIdx.y * 64, b = blockIdx.z;
  const int tid = threadIdx.x;
#pragma unroll
  for (int i = 0; i < 8; ++i) {
    int idx = tid + i * 256;            // 2048 short2 units
    int row = idx >> 5, col2 = idx & 31;
    short2v v = *(const short2v*)(in + (size_t)((b << 11) + t0 + row) * 512 + l0 + col2 * 2);
    tile[row][col2 * 2] = v[0];
    tile[row][col2 * 2 + 1] = v[1];
  }
  __syncthreads();
#pragma unroll
  for (int i = 0; i < 8; ++i) {
    int idx = tid + i * 256;
    int row = idx >> 5, col2 = idx & 31;  // row: l index, cols: t
    short2v v;
    v[0] = tile[col2 * 2][row];
    v[1] = tile[col2 * 2 + 1][row];
    *(short2v*)(out + (size_t)((b << 9) + l0 + row) * 2048 + t0 + col2 * 2) = v;
  }
}

// ---------------- generic NT bf16 GEMM: C[m][n] = sum_k A[m][k]*B[n][k] ----------------
// 128x128 tile, BK=64, 4 waves (2x2), global_load_lds staging with XOR-swizzled source.
__global__ __launch_bounds__(256) void gemm_nt(
    const short* __restrict__ A, const short* __restrict__ B,
    float* __restrict__ Cf, short* __restrict__ Cb,
    int M, int N, int K, int lda, int ldb, int ldc,
    long aZ, long bZ, long cZo, long cZi, int zmod)
{
  const int bx = blockIdx.x, by = blockIdx.y, bz = blockIdx.z;
  A += (long)bz * aZ;
  B += (long)(bz % zmod) * bZ;
  const long coff = (long)(bz / zmod) * cZo + (long)(bz % zmod) * cZi;

  const int tid = threadIdx.x, wid = tid >> 6, L = tid & 63;
  const int g = L >> 4, r16 = L & 15, wr = wid >> 1, wc = wid & 1;
  const int rl = L >> 3, ru = L & 7;  // staging row-in-8 / unit

  __shared__ short Asm[128 * 64], Bsm[128 * 64];
  char* Ab = (char*)Asm;
  char* Bb = (char*)Bsm;

  const f32x4 fz = {0.f, 0.f, 0.f, 0.f};
  f32x4 acc[4][4];
#pragma unroll
  for (int m = 0; m < 4; ++m)
#pragma unroll
    for (int n = 0; n < 4; ++n) acc[m][n] = fz;

  const int aRow0 = bx * 128, bRow0 = by * 128;

  for (int kt = 0; kt < K; kt += 64) {
#pragma unroll
    for (int i = 0; i < 4; ++i) {
      int row = i * 32 + wid * 8 + rl;
      const short* gp = A + (size_t)(aRow0 + row) * lda + kt + ((ru ^ rl) * 8);
      gload_lds16(gp, Ab + (i * 32 + wid * 8) * 128);
    }
#pragma unroll
    for (int i = 0; i < 4; ++i) {
      int row = i * 32 + wid * 8 + rl;
      const short* gp = B + (size_t)(bRow0 + row) * ldb + kt + ((ru ^ rl) * 8);
      gload_lds16(gp, Bb + (i * 32 + wid * 8) * 128);
    }
    __syncthreads();
#pragma unroll
    for (int kk = 0; kk < 2; ++kk) {
      short8 a[4], b2[4];
#pragma unroll
      for (int m = 0; m < 4; ++m) {
        int row = wr * 64 + m * 16 + r16;
        a[m] = *(const short8*)(Ab + row * 128 + (((kk * 4 + g) ^ (row & 7)) << 4));
      }
#pragma unroll
      for (int n = 0; n < 4; ++n) {
        int row = wc * 64 + n * 16 + r16;
        b2[n] = *(const short8*)(Bb + row * 128 + (((kk * 4 + g) ^ (row & 7)) << 4));
      }
#pragma unroll
      for (int m = 0; m < 4; ++m)
#pragma unroll
        for (int n = 0; n < 4; ++n) acc[m][n] = mfma16(a[m], b2[n], acc[m][n]);
    }
    __syncthreads();
  }

#pragma unroll
  for (int m = 0; m < 4; ++m) {
    int row0 = aRow0 + wr * 64 + m * 16 + g * 4;
#pragma unroll
    for (int n = 0; n < 4; ++n) {
      int col = bRow0 + wc * 64 + n * 16 + r16;
#pragma unroll
      for (int e = 0; e < 4; ++e) {
        long idx = coff + (long)(row0 + e) * ldc + col;
        if (Cf) Cf[idx] = acc[m][n][e];
        if (Cb) Cb[idx] = f2bf(acc[m][n][e]);
      }
    }
  }
}

// ---------------- fused q_lat + causal flash attention over latent dim ----------------
// grid (8, 16, 2) = (qtile-pair, head, batch); 512 threads (8 waves x 16 q-rows).
// Per rep: qt = bx or 15-bx  -> constant 34 k-tile iterations per WG (causal balance).
//
// REGISTER BUDGET (R3/R4 lesson): the RA's DEFAULT occupancy target is 4 waves/EU ->
// it capped arch VGPRs at 128 (=512-reg pool / 4) and spilled ~60 regs in the k-loop
// (455MB phantom WRITE_SIZE, MfmaUtil 7.6%). __launch_bounds__' 2nd arg is only a
// LOWER bound on waves/EU and cannot lower the target. amdgpu_waves_per_eu(2,2) pins
// the target to exactly 2 waves/EU (which the 144KiB LDS already forces: 1 WG/CU =
// 8 waves / 4 SIMD), unlocking the 256 arch-VGPR budget. Demand: acc[32]=128 (acc
// file) + qf[16]=64 + temps ~110 arch -> fits.
__global__ __launch_bounds__(512)
__attribute__((amdgpu_waves_per_eu(2, 2)))
void flash_mhla(
    const short* __restrict__ x_bf,   // [2][2048][2048]
    const short* __restrict__ kabsT,  // [16][512][128]
    const short* __restrict__ ckv,    // [2][2048][512]
    const short* __restrict__ ckvT,   // [2][512][2048]
    short* __restrict__ out_lat)      // [2][16][2048][512]
{
  const int h = blockIdx.y, b = blockIdx.z;
  const int tid = threadIdx.x;
  const int wid = tid >> 6, L = tid & 63, g = L >> 4, r16 = L & 15;

  __shared__ short lds[73728];        // K[64][512] | V^T[512][64] | P[8][16][64]  = 144 KiB
  char* ldsb = (char*)lds;
  char* Vb = ldsb + 65536;
  char* Pb = ldsb + 131072 + wid * 2048;

  const float CE = 1.4426950408889634f / 11.313708498984760f;  // log2(e)/sqrt(128)
  const f32x4 fz = {0.f, 0.f, 0.f, 0.f};

  for (int rep = 0; rep < 2; ++rep) {
    const int qt = rep ? 15 - (int)blockIdx.x : (int)blockIdx.x;
    const int q0 = qt * 128;

    // ---- Phase 0: Q'[16 rows][512] = x[rows][h*128..+128] @ kabsT[h]  (per wave) ----
    short8 xa[4];
    {
      const short* xp = x_bf + ((size_t)(b * 2048 + q0 + wid * 16 + r16)) * 2048 + h * 128 + g * 8;
#pragma unroll
      for (int kk = 0; kk < 4; ++kk) xa[kk] = *(const short8*)(xp + kk * 32);
    }
    {
      const short* kb = kabsT + (size_t)h * 65536;
#pragma unroll
      for (int n = 0; n < 32; ++n) {
        f32x4 a0 = fz;
#pragma unroll
        for (int kk = 0; kk < 4; ++kk) {
          short8 bf = *(const short8*)(kb + (n * 16 + r16) * 128 + kk * 32 + g * 8);
          a0 = mfma16(xa[kk], bf, a0);
        }
#pragma unroll
        for (int e = 0; e < 4; ++e) {   // wave-local scatter to q_buf (K/V region)
          int row = wid * 16 + g * 4 + e;
          int colb = ((n * 16 + r16) * 2) ^ ((row & 7) << 4);
          *(short*)(ldsb + row * 1024 + colb) = f2bf(a0[e]);
        }
      }
    }
    short8 qf[16];                      // wave-local readback of scores A-frags
    {
      int row = wid * 16 + r16;
#pragma unroll
      for (int kk = 0; kk < 16; ++kk)
        qf[kk] = *(const short8*)(ldsb + row * 1024 + (((kk * 4 + g) ^ (row & 7)) << 4));
    }
    __syncthreads();  // q_buf reads done before staging overwrites

    f32x4 acc[32];
#pragma unroll
    for (int n = 0; n < 32; ++n) acc[n] = fz;
    float m_run[4] = {-1e30f, -1e30f, -1e30f, -1e30f};
    float l_run[4] = {0.f, 0.f, 0.f, 0.f};

    const int nkt = 2 * qt + 2;
    for (int kt = 0; kt < nkt; ++kt) {
      const int s0 = kt * 64;
      // stage K tile [64 keys][512 lat] (source pre-swizzled by row&7, 16B units)
#pragma unroll
      for (int i = 0; i < 8; ++i) {
        int krow = i * 8 + wid;
        const short* gp = ckv + (size_t)(b * 2048 + s0 + krow) * 512 + ((L ^ (krow & 7)) * 8);
        gload_lds16(gp, ldsb + krow * 1024);
      }
      // stage V^T tile [512 lat][64 keys]
#pragma unroll
      for (int i = 0; i < 8; ++i) {
        int lat0 = (i * 8 + wid) * 8;
        int lat = lat0 + (L >> 3);
        const short* gp = ckvT + (size_t)(b * 512 + lat) * 2048 + s0 + (((L & 7) ^ (lat & 7)) * 8);
        gload_lds16(gp, Vb + lat0 * 128);
      }
      __syncthreads();

      // scores S[16 q][64 keys], K-dim 512
      f32x4 s[4] = {fz, fz, fz, fz};
#pragma unroll
      for (int kk = 0; kk < 16; ++kk)
#pragma unroll
        for (int n = 0; n < 4; ++n) {
          int row = n * 16 + r16;
          short8 kf = *(const short8*)(ldsb + row * 1024 + (((kk * 4 + g) ^ (row & 7)) << 4));
          s[n] = mfma16(qf[kk], kf, s[n]);
        }

      if (s0 + 63 > q0 + wid * 16) {  // causal mask (only straddling tiles)
#pragma unroll
        for (int n = 0; n < 4; ++n)
#pragma unroll
          for (int e = 0; e < 4; ++e)
            if (s0 + n * 16 + r16 > q0 + wid * 16 + g * 4 + e) s[n][e] = -3e38f;
      }

      // row max (rows live in 16-lane groups)
      float tm[4];
#pragma unroll
      for (int e = 0; e < 4; ++e)
        tm[e] = fmaxf(fmaxf(s[0][e], s[1][e]), fmaxf(s[2][e], s[3][e]));
#pragma unroll
      for (int off = 1; off <= 8; off <<= 1)
#pragma unroll
        for (int e = 0; e < 4; ++e) tm[e] = fmaxf(tm[e], __shfl_xor(tm[e], off, 64));

      // defer-max (T13): only rescale when unscaled growth > 62 (=> P <= ~2^8)
      float growth = 0.f;
#pragma unroll
      for (int e = 0; e < 4; ++e) growth = fmaxf(growth, tm[e] - m_run[e]);
      if (!__all(growth <= 62.f)) {
#pragma unroll
        for (int e = 0; e < 4; ++e) {
          float mn = fmaxf(m_run[e], tm[e]);
          float f = exp2f((m_run[e] - mn) * CE);
          m_run[e] = mn;
          l_run[e] *= f;
#pragma unroll
          for (int n = 0; n < 32; ++n) acc[n][e] *= f;
        }
      }

      float rs[4] = {0.f, 0.f, 0.f, 0.f};
#pragma unroll
      for (int n = 0; n < 4; ++n)
#pragma unroll
        for (int e = 0; e < 4; ++e) {
          float p = exp2f((s[n][e] - m_run[e]) * CE);
          s[n][e] = p;
          rs[e] += p;
        }
#pragma unroll
      for (int off = 1; off <= 8; off <<= 1)
#pragma unroll
        for (int e = 0; e < 4; ++e) rs[e] += __shfl_xor(rs[e], off, 64);
#pragma unroll
      for (int e = 0; e < 4; ++e) l_run[e] += rs[e];

      // P -> per-wave-private LDS (bf16), then read back as A-frags (wave-local ordering)
#pragma unroll
      for (int n = 0; n < 4; ++n)
#pragma unroll
        for (int e = 0; e < 4; ++e) {
          int row = g * 4 + e;
          int unit = (n * 2 + (r16 >> 3)) ^ (row & 7);
          *(short*)(Pb + row * 128 + unit * 16 + (r16 & 7) * 2) = f2bf(s[n][e]);
        }
      short8 pa[2];
#pragma unroll
      for (int kk = 0; kk < 2; ++kk)
        pa[kk] = *(const short8*)(Pb + r16 * 128 + (((kk * 4 + g) ^ (r16 & 7)) << 4));

      // PV: acc[16 q][512 lat] += P[16][64] @ V[64][512]
#pragma unroll
      for (int n = 0; n < 32; ++n)
#pragma unroll
        for (int kk = 0; kk < 2; ++kk) {
          int row = n * 16 + r16;
          short8 vf = *(const short8*)(Vb + row * 128 + (((kk * 4 + g) ^ (row & 7)) << 4));
          acc[n] = mfma16(pa[kk], vf, acc[n]);
        }
      __syncthreads();
    }

    // epilogue: normalize, wave-local LDS roundtrip, coalesced bf16 store
    float inv[4];
#pragma unroll
    for (int e = 0; e < 4; ++e) inv[e] = 1.f / l_run[e];
#pragma unroll
    for (int n = 0; n < 32; ++n)
#pragma unroll
      for (int e = 0; e < 4; ++e) {
        int row = wid * 16 + g * 4 + e;
        int colb = ((n * 16 + r16) * 2) ^ ((row & 7) << 4);
        *(short*)(ldsb + row * 1024 + colb) = f2bf(acc[n][e] * inv[e]);
      }
    short* outp = out_lat + ((size_t)(b * 16 + h) * 2048 + q0) * 512;
#pragma unroll
    for (int r = 0; r < 16; ++r) {
      int row = wid * 16 + r;
      short8 v = *(const short8*)(ldsb + row * 1024 + ((L ^ (row & 7)) << 4));
      *(short8*)(outp + (size_t)row * 512 + L * 8) = v;
    }
  }
}

// ---------------- host ----------------

extern "C" void kernel_launch(void* const* d_in, const int* in_sizes, int n_in,
                              void* d_out, int out_size, void* d_ws, size_t ws_size,
                              hipStream_t stream) {
  const float* x    = (const float*)d_in[0];
  const float* Wdq  = (const float*)d_in[1];
  const float* Wdkv = (const float*)d_in[2];
  const float* Wuk  = (const float*)d_in[3];
  const float* Wuv  = (const float*)d_in[4];
  const float* Wo   = (const float*)d_in[5];
  float* y     = (float*)d_out;                        // [2][2048][2048]
  float* ckv_f = y + (size_t)2 * 2048 * 2048;          // [2][2048][512]

  char* w = (char*)d_ws;
  auto alloc = [&](size_t bytes) { char* p = w; w += (bytes + 255) & ~(size_t)255; return p; };
  short* x_bf   = (short*)alloc((size_t)2 * 2048 * 2048 * 2);
  short* wdkv   = (short*)alloc((size_t)512 * 2048 * 2);
  short* wukT   = (short*)alloc((size_t)512 * 2048 * 2);
  short* wdqT   = (short*)alloc((size_t)2048 * 512 * 2);
  short* wuvT   = (short*)alloc((size_t)512 * 2048 * 2);
  short* wo     = (short*)alloc((size_t)2048 * 2048 * 2);
  short* m1     = (short*)alloc((size_t)512 * 512 * 2);
  short* kabs   = (short*)alloc((size_t)2048 * 512 * 2);
  short* kabsT  = (short*)alloc((size_t)16 * 512 * 128 * 2);
  short* vflat  = (short*)alloc((size_t)512 * 2048 * 2);
  short* vabsT  = (short*)alloc((size_t)16 * 128 * 512 * 2);
  short* ckvb   = (short*)alloc((size_t)2 * 2048 * 512 * 2);
  short* ckvT   = (short*)alloc((size_t)2 * 512 * 2048 * 2);
  short* outlat = (short*)alloc((size_t)2 * 16 * 2048 * 512 * 2);

  // converts / weight transposes
  conv_bf16<<<8192, 256, 0, stream>>>(x, x_bf, 2097152);
  conv_bf16<<<1024, 256, 0, stream>>>(Wdkv, wdkv, 262144);
  conv_bf16<<<4096, 256, 0, stream>>>(Wo, wo, 1048576);
  transpose_f32_bf16<<<4096, 256, 0, stream>>>(Wuk, wukT, 2048, 512);
  transpose_f32_bf16<<<4096, 256, 0, stream>>>(Wdq, wdqT, 512, 2048);
  transpose_f32_bf16<<<4096, 256, 0, stream>>>(Wuv, wuvT, 2048, 512);

  // M1 = W_uk^T W_uk  (bf16 out; exactly symmetric by construction)
  gemm_nt<<<dim3(4, 4, 1), 256, 0, stream>>>(wukT, wukT, nullptr, m1,
      512, 512, 2048, 2048, 2048, 512, 0, 0, 0, 0, 1);
  // k_abs = W_dq^T @ M1  (uses M1 symmetry for the NT form)
  gemm_nt<<<dim3(16, 4, 1), 256, 0, stream>>>(wdqT, m1, nullptr, kabs,
      2048, 512, 512, 512, 512, 512, 0, 0, 0, 0, 1);
  // v_flat = W_uv^T @ W_o^T
  gemm_nt<<<dim3(4, 16, 1), 256, 0, stream>>>(wuvT, wo, nullptr, vflat,
      512, 2048, 2048, 2048, 2048, 2048, 0, 0, 0, 0, 1);
  // c_kv = x @ W_dkv^T  -> fp32 output chunk 2 + bf16 copy
  gemm_nt<<<dim3(32, 4, 1), 256, 0, stream>>>(x_bf, wdkv, ckv_f, ckvb,
      4096, 512, 2048, 2048, 2048, 512, 0, 0, 0, 0, 1);

  trans_kabs<<<4096, 256, 0, stream>>>(kabs, kabsT);
  trans_vabs<<<4096, 256, 0, stream>>>(vflat, vabsT);
  trans_ckvT<<<dim3(32, 8, 2), 256, 0, stream>>>(ckvb, ckvT);

  // fused q_lat + causal flash attention (latent K=V), balanced qtile pairs
  flash_mhla<<<dim3(8, 16, 2), 512, 0, stream>>>(x_bf, kabsT, ckvb, ckvT, outlat);

  // y[b][t][h*128+d] = out_lat[b][h][t][:] @ v_abs[h]
  gemm_nt<<<dim3(16, 1, 32), 256, 0, stream>>>(outlat, vabsT, y, nullptr,
      2048, 128, 512, 512, 512, 2048,
      (long)2048 * 512, (long)128 * 512, (long)2048 * 2048, 128L, 16);
}

// Round 6
// 929.184 us; speedup vs baseline: 1.0965x; 1.0965x over previous
//
#include <hip/hip_runtime.h>
#include <stdint.h>

typedef __attribute__((ext_vector_type(8))) short short8;   // 8 x bf16 (4 VGPR)
typedef __attribute__((ext_vector_type(4))) short short4v;
typedef __attribute__((ext_vector_type(2))) short short2v;
typedef __attribute__((ext_vector_type(4))) float f32x4;
typedef __attribute__((ext_vector_type(8))) __bf16 bf16x8;

__device__ __forceinline__ short f2bf(float f) {
  unsigned u = __builtin_bit_cast(unsigned, f);
  u = (u + 0x7FFFu + ((u >> 16) & 1u)) >> 16;   // RNE
  return (short)u;
}

__device__ __forceinline__ f32x4 mfma16(short8 a, short8 b, f32x4 c) {
  return __builtin_amdgcn_mfma_f32_16x16x32_bf16(
      __builtin_bit_cast(bf16x8, a), __builtin_bit_cast(bf16x8, b), c, 0, 0, 0);
}

// async global->LDS, 16B per lane. ldsptr must be wave-uniform; HW writes base + lane*16.
__device__ __forceinline__ void gload_lds16(const void* g, void* l) {
  __builtin_amdgcn_global_load_lds(
      (const __attribute__((address_space(1))) unsigned int*)g,
      (__attribute__((address_space(3))) unsigned int*)l, 16, 0, 0);
}

// ---------------- small data-movement kernels ----------------

__global__ void conv_bf16(const float* __restrict__ in, short* __restrict__ out, int n4) {
  int i = blockIdx.x * 256 + threadIdx.x;
  if (i >= n4) return;
  f32x4 v = ((const f32x4*)in)[i];
  short4v o;
  o[0] = f2bf(v[0]); o[1] = f2bf(v[1]); o[2] = f2bf(v[2]); o[3] = f2bf(v[3]);
  ((short4v*)out)[i] = o;
}

// out[c][r] = in[r][c]  (in: [R][C] f32, out: [C][R] bf16)
__global__ void transpose_f32_bf16(const float* __restrict__ in, short* __restrict__ out,
                                   int R, int C) {
  int o = blockIdx.x * 256 + threadIdx.x;
  if (o >= R * C) return;
  int c = o / R, r = o - c * R;
  out[o] = f2bf(in[(size_t)r * C + c]);
}

// kabsT[h][l][d] = kabs[(h*128+d)*512 + l]   (16*512*128 elems)
__global__ void trans_kabs(const short* __restrict__ in, short* __restrict__ out) {
  int o = blockIdx.x * 256 + threadIdx.x;
  int h = o >> 16, rem = o & 65535, l = rem >> 7, d = rem & 127;
  out[o] = in[((h << 7) + d) * 512 + l];
}

// vabsT[h][d][l] = vflat[l*2048 + h*128 + d]  (16*128*512 elems)
__global__ void trans_vabs(const short* __restrict__ in, short* __restrict__ out) {
  int o = blockIdx.x * 256 + threadIdx.x;
  int h = o >> 16, rem = o & 65535, d = rem >> 9, l = rem & 511;
  out[o] = in[l * 2048 + (h << 7) + d];
}

// ckvT[(b*512+l)*2048+t] = ckv[(b*2048+t)*512+l]
// LDS-tiled 64x64 transpose: coalesced reads AND writes.
// grid (32, 8, 2) = (t-tile, l-tile, b); 256 threads.
__global__ __launch_bounds__(256) void trans_ckvT(const short* __restrict__ in,
                                                  short* __restrict__ out) {
  __shared__ short tile[64][66];
  const int t0 = blockIdx.x * 64, l0 = blockIdx.y * 64, b = blockIdx.z;
  const int tid = threadIdx.x;
#pragma unroll
  for (int i = 0; i < 8; ++i) {
    int idx = tid + i * 256;            // 2048 short2 units
    int row = idx >> 5, col2 = idx & 31;
    short2v v = *(const short2v*)(in + (size_t)((b << 11) + t0 + row) * 512 + l0 + col2 * 2);
    tile[row][col2 * 2] = v[0];
    tile[row][col2 * 2 + 1] = v[1];
  }
  __syncthreads();
#pragma unroll
  for (int i = 0; i < 8; ++i) {
    int idx = tid + i * 256;
    int row = idx >> 5, col2 = idx & 31;  // row: l index, cols: t
    short2v v;
    v[0] = tile[col2 * 2][row];
    v[1] = tile[col2 * 2 + 1][row];
    *(short2v*)(out + (size_t)((b << 9) + l0 + row) * 2048 + t0 + col2 * 2) = v;
  }
}

// ---------------- generic NT bf16 GEMM: C[m][n] = sum_k A[m][k]*B[n][k] ----------------
// 128x128 tile, BK=64, 4 waves (2x2), global_load_lds staging with XOR-swizzled source.
__global__ __launch_bounds__(256) void gemm_nt(
    const short* __restrict__ A, const short* __restrict__ B,
    float* __restrict__ Cf, short* __restrict__ Cb,
    int M, int N, int K, int lda, int ldb, int ldc,
    long aZ, long bZ, long cZo, long cZi, int zmod)
{
  const int bx = blockIdx.x, by = blockIdx.y, bz = blockIdx.z;
  A += (long)bz * aZ;
  B += (long)(bz % zmod) * bZ;
  const long coff = (long)(bz / zmod) * cZo + (long)(bz % zmod) * cZi;

  const int tid = threadIdx.x, wid = tid >> 6, L = tid & 63;
  const int g = L >> 4, r16 = L & 15, wr = wid >> 1, wc = wid & 1;
  const int rl = L >> 3, ru = L & 7;  // staging row-in-8 / unit

  __shared__ short Asm[128 * 64], Bsm[128 * 64];
  char* Ab = (char*)Asm;
  char* Bb = (char*)Bsm;

  const f32x4 fz = {0.f, 0.f, 0.f, 0.f};
  f32x4 acc[4][4];
#pragma unroll
  for (int m = 0; m < 4; ++m)
#pragma unroll
    for (int n = 0; n < 4; ++n) acc[m][n] = fz;

  const int aRow0 = bx * 128, bRow0 = by * 128;

  for (int kt = 0; kt < K; kt += 64) {
#pragma unroll
    for (int i = 0; i < 4; ++i) {
      int row = i * 32 + wid * 8 + rl;
      const short* gp = A + (size_t)(aRow0 + row) * lda + kt + ((ru ^ rl) * 8);
      gload_lds16(gp, Ab + (i * 32 + wid * 8) * 128);
    }
#pragma unroll
    for (int i = 0; i < 4; ++i) {
      int row = i * 32 + wid * 8 + rl;
      const short* gp = B + (size_t)(bRow0 + row) * ldb + kt + ((ru ^ rl) * 8);
      gload_lds16(gp, Bb + (i * 32 + wid * 8) * 128);
    }
    __syncthreads();
#pragma unroll
    for (int kk = 0; kk < 2; ++kk) {
      short8 a[4], b2[4];
#pragma unroll
      for (int m = 0; m < 4; ++m) {
        int row = wr * 64 + m * 16 + r16;
        a[m] = *(const short8*)(Ab + row * 128 + (((kk * 4 + g) ^ (row & 7)) << 4));
      }
#pragma unroll
      for (int n = 0; n < 4; ++n) {
        int row = wc * 64 + n * 16 + r16;
        b2[n] = *(const short8*)(Bb + row * 128 + (((kk * 4 + g) ^ (row & 7)) << 4));
      }
#pragma unroll
      for (int m = 0; m < 4; ++m)
#pragma unroll
        for (int n = 0; n < 4; ++n) acc[m][n] = mfma16(a[m], b2[n], acc[m][n]);
    }
    __syncthreads();
  }

#pragma unroll
  for (int m = 0; m < 4; ++m) {
    int row0 = aRow0 + wr * 64 + m * 16 + g * 4;
#pragma unroll
    for (int n = 0; n < 4; ++n) {
      int col = bRow0 + wc * 64 + n * 16 + r16;
#pragma unroll
      for (int e = 0; e < 4; ++e) {
        long idx = coff + (long)(row0 + e) * ldc + col;
        if (Cf) Cf[idx] = acc[m][n][e];
        if (Cb) Cb[idx] = f2bf(acc[m][n][e]);
      }
    }
  }
}

// ---------------- fused q_lat + causal flash attention over latent dim ----------------
// grid (8, 16, 2) = (qtile-pair, head, batch); 512 threads (8 waves x 16 q-rows).
// Per rep: qt = bx or 15-bx  -> constant 36 k-tile passes per WG (causal balance).
//
// REGISTER BUDGET (R3-R5 lesson): three occupancy hints produced byte-identical
// codegen (VGPR=128 + ~390MB spill). HIP __launch_bounds__ itself lowers to
// "amdgpu-waves-per-eu" and CONFLICTS with an explicit amdgpu_waves_per_eu attr.
// Fix is structural: lat-half split (lh=0/1 passes) cuts acc 32->16 f32x4, so
// demand ~190 regs fits any plausible budget. qf (Q' frags, full 512-lat) is
// computed once per q-tile and reused across both lh passes. Attribute-only
// occupancy spec (no __launch_bounds__), flat wg size pinned to 512.
__global__
__attribute__((amdgpu_flat_work_group_size(512, 512), amdgpu_waves_per_eu(2, 2)))
void flash_mhla(
    const short* __restrict__ x_bf,   // [2][2048][2048]
    const short* __restrict__ kabsT,  // [16][512][128]
    const short* __restrict__ ckv,    // [2][2048][512]
    const short* __restrict__ ckvT,   // [2][512][2048]
    short* __restrict__ out_lat)      // [2][16][2048][512]
{
  const int h = blockIdx.y, b = blockIdx.z;
  const int tid = threadIdx.x;
  const int wid = tid >> 6, L = tid & 63, g = L >> 4, r16 = L & 15;

  __shared__ short lds[73728];        // Q'[128][512] overlay {K[64][512] | V^T[256][64]} | P
  char* ldsb = (char*)lds;            // K region: 64KB (also Q' rows 0..63)
  char* Vb = ldsb + 65536;            // V-half region: 32KB used (Q' rows 64..127 span here)
  char* Pb = ldsb + 131072 + wid * 2048;

  const float CE = 1.4426950408889634f / 11.313708498984760f;  // log2(e)/sqrt(128)
  const f32x4 fz = {0.f, 0.f, 0.f, 0.f};

  for (int rep = 0; rep < 2; ++rep) {
    const int qt = rep ? 15 - (int)blockIdx.x : (int)blockIdx.x;
    const int q0 = qt * 128;

    // ---- Phase 0 (once per q-tile): Q'[16 rows][512] = x[rows][h*128..+128] @ kabsT[h] ----
    {
      short8 xa[4];
      const short* xp = x_bf + ((size_t)(b * 2048 + q0 + wid * 16 + r16)) * 2048 + h * 128 + g * 8;
#pragma unroll
      for (int kk = 0; kk < 4; ++kk) xa[kk] = *(const short8*)(xp + kk * 32);
      const short* kb = kabsT + (size_t)h * 65536;
#pragma unroll
      for (int n = 0; n < 32; ++n) {
        f32x4 a0 = fz;
#pragma unroll
        for (int kk = 0; kk < 4; ++kk) {
          short8 bf = *(const short8*)(kb + (n * 16 + r16) * 128 + kk * 32 + g * 8);
          a0 = mfma16(xa[kk], bf, a0);
        }
#pragma unroll
        for (int e = 0; e < 4; ++e) {   // wave-local scatter to Q' buffer (K+V regions)
          int row = wid * 16 + g * 4 + e;
          int colb = ((n * 16 + r16) * 2) ^ ((row & 7) << 4);
          *(short*)(ldsb + row * 1024 + colb) = f2bf(a0[e]);
        }
      }
    }
    short8 qf[16];                      // full-512-lat Q' A-frags; live across BOTH lh passes
    {
      int row = wid * 16 + r16;
#pragma unroll
      for (int kk = 0; kk < 16; ++kk)
        qf[kk] = *(const short8*)(ldsb + row * 1024 + (((kk * 4 + g) ^ (row & 7)) << 4));
    }
    __syncthreads();  // Q' reads done before staging overwrites

    const int nkt = 2 * qt + 2;

    for (int lh = 0; lh < 2; ++lh) {    // lat half: acc covers lat [lh*256, lh*256+256)
      f32x4 acc[16];
#pragma unroll
      for (int n = 0; n < 16; ++n) acc[n] = fz;
      float m_run[4] = {-1e30f, -1e30f, -1e30f, -1e30f};
      float l_run[4] = {0.f, 0.f, 0.f, 0.f};

      for (int kt = 0; kt < nkt; ++kt) {
        const int s0 = kt * 64;
        // stage K tile [64 keys][512 lat] (source pre-swizzled by row&7, 16B units)
#pragma unroll
        for (int i = 0; i < 8; ++i) {
          int krow = i * 8 + wid;
          const short* gp = ckv + (size_t)(b * 2048 + s0 + krow) * 512 + ((L ^ (krow & 7)) * 8);
          gload_lds16(gp, ldsb + krow * 1024);
        }
        // stage V^T half-tile [256 lat][64 keys]
#pragma unroll
        for (int i = 0; i < 4; ++i) {
          int lat0 = (i * 8 + wid) * 8;
          int lat = lat0 + (L >> 3);
          const short* gp = ckvT + (size_t)(b * 512 + lh * 256 + lat) * 2048 + s0 +
                            (((L & 7) ^ (lat & 7)) * 8);
          gload_lds16(gp, Vb + lat0 * 128);
        }
        __syncthreads();

        // scores S[16 q][64 keys], K-dim 512 (recomputed per lh; qf reused)
        f32x4 s[4] = {fz, fz, fz, fz};
#pragma unroll
        for (int kk = 0; kk < 16; ++kk)
#pragma unroll
          for (int n = 0; n < 4; ++n) {
            int row = n * 16 + r16;
            short8 kf = *(const short8*)(ldsb + row * 1024 + (((kk * 4 + g) ^ (row & 7)) << 4));
            s[n] = mfma16(qf[kk], kf, s[n]);
          }

        if (s0 + 63 > q0 + wid * 16) {  // causal mask (only straddling tiles)
#pragma unroll
          for (int n = 0; n < 4; ++n)
#pragma unroll
            for (int e = 0; e < 4; ++e)
              if (s0 + n * 16 + r16 > q0 + wid * 16 + g * 4 + e) s[n][e] = -3e38f;
        }

        // row max (rows live in 16-lane groups)
        float tm[4];
#pragma unroll
        for (int e = 0; e < 4; ++e)
          tm[e] = fmaxf(fmaxf(s[0][e], s[1][e]), fmaxf(s[2][e], s[3][e]));
#pragma unroll
        for (int off = 1; off <= 8; off <<= 1)
#pragma unroll
          for (int e = 0; e < 4; ++e) tm[e] = fmaxf(tm[e], __shfl_xor(tm[e], off, 64));

        // defer-max (T13): only rescale when unscaled growth > 62 (=> P <= ~2^8)
        float growth = 0.f;
#pragma unroll
        for (int e = 0; e < 4; ++e) growth = fmaxf(growth, tm[e] - m_run[e]);
        if (!__all(growth <= 62.f)) {
#pragma unroll
          for (int e = 0; e < 4; ++e) {
            float mn = fmaxf(m_run[e], tm[e]);
            float f = exp2f((m_run[e] - mn) * CE);
            m_run[e] = mn;
            l_run[e] *= f;
#pragma unroll
            for (int n = 0; n < 16; ++n) acc[n][e] *= f;
          }
        }

        float rs[4] = {0.f, 0.f, 0.f, 0.f};
#pragma unroll
        for (int n = 0; n < 4; ++n)
#pragma unroll
          for (int e = 0; e < 4; ++e) {
            float p = exp2f((s[n][e] - m_run[e]) * CE);
            s[n][e] = p;
            rs[e] += p;
          }
#pragma unroll
        for (int off = 1; off <= 8; off <<= 1)
#pragma unroll
          for (int e = 0; e < 4; ++e) rs[e] += __shfl_xor(rs[e], off, 64);
#pragma unroll
        for (int e = 0; e < 4; ++e) l_run[e] += rs[e];

        // P -> per-wave-private LDS (bf16), then read back as A-frags (wave-local ordering)
#pragma unroll
        for (int n = 0; n < 4; ++n)
#pragma unroll
          for (int e = 0; e < 4; ++e) {
            int row = g * 4 + e;
            int unit = (n * 2 + (r16 >> 3)) ^ (row & 7);
            *(short*)(Pb + row * 128 + unit * 16 + (r16 & 7) * 2) = f2bf(s[n][e]);
          }
        short8 pa[2];
#pragma unroll
        for (int kk = 0; kk < 2; ++kk)
          pa[kk] = *(const short8*)(Pb + r16 * 128 + (((kk * 4 + g) ^ (r16 & 7)) << 4));

        // PV: acc[16 q][256 lat] += P[16][64] @ V[64][lh*256..+256]
#pragma unroll
        for (int n = 0; n < 16; ++n)
#pragma unroll
          for (int kk = 0; kk < 2; ++kk) {
            int row = n * 16 + r16;
            short8 vf = *(const short8*)(Vb + row * 128 + (((kk * 4 + g) ^ (row & 7)) << 4));
            acc[n] = mfma16(pa[kk], vf, acc[n]);
          }
        __syncthreads();
      }

      // epilogue: normalize, wave-local LDS roundtrip (512B rows), coalesced bf16 store
      float inv[4];
#pragma unroll
      for (int e = 0; e < 4; ++e) inv[e] = 1.f / l_run[e];
#pragma unroll
      for (int n = 0; n < 16; ++n)
#pragma unroll
        for (int e = 0; e < 4; ++e) {
          int row = wid * 16 + g * 4 + e;
          int colb = ((n * 16 + r16) * 2) ^ ((row & 7) << 4);
          *(short*)(ldsb + row * 512 + colb) = f2bf(acc[n][e] * inv[e]);
        }
      short* outp = out_lat + ((size_t)(b * 16 + h) * 2048 + q0) * 512 + lh * 256;
#pragma unroll
      for (int r = 0; r < 8; ++r) {
        int row = wid * 16 + r * 2 + (L >> 5);
        int lane = L & 31;
        short8 v = *(const short8*)(ldsb + row * 512 + ((lane << 4) ^ ((row & 7) << 4)));
        *(short8*)(outp + (size_t)row * 512 + lane * 8) = v;
      }
      __syncthreads();  // epilogue LDS reads done before next pass/rep overwrites
    }
  }
}

// ---------------- host ----------------

extern "C" void kernel_launch(void* const* d_in, const int* in_sizes, int n_in,
                              void* d_out, int out_size, void* d_ws, size_t ws_size,
                              hipStream_t stream) {
  const float* x    = (const float*)d_in[0];
  const float* Wdq  = (const float*)d_in[1];
  const float* Wdkv = (const float*)d_in[2];
  const float* Wuk  = (const float*)d_in[3];
  const float* Wuv  = (const float*)d_in[4];
  const float* Wo   = (const float*)d_in[5];
  float* y     = (float*)d_out;                        // [2][2048][2048]
  float* ckv_f = y + (size_t)2 * 2048 * 2048;          // [2][2048][512]

  char* w = (char*)d_ws;
  auto alloc = [&](size_t bytes) { char* p = w; w += (bytes + 255) & ~(size_t)255; return p; };
  short* x_bf   = (short*)alloc((size_t)2 * 2048 * 2048 * 2);
  short* wdkv   = (short*)alloc((size_t)512 * 2048 * 2);
  short* wukT   = (short*)alloc((size_t)512 * 2048 * 2);
  short* wdqT   = (short*)alloc((size_t)2048 * 512 * 2);
  short* wuvT   = (short*)alloc((size_t)512 * 2048 * 2);
  short* wo     = (short*)alloc((size_t)2048 * 2048 * 2);
  short* m1     = (short*)alloc((size_t)512 * 512 * 2);
  short* kabs   = (short*)alloc((size_t)2048 * 512 * 2);
  short* kabsT  = (short*)alloc((size_t)16 * 512 * 128 * 2);
  short* vflat  = (short*)alloc((size_t)512 * 2048 * 2);
  short* vabsT  = (short*)alloc((size_t)16 * 128 * 512 * 2);
  short* ckvb   = (short*)alloc((size_t)2 * 2048 * 512 * 2);
  short* ckvT   = (short*)alloc((size_t)2 * 512 * 2048 * 2);
  short* outlat = (short*)alloc((size_t)2 * 16 * 2048 * 512 * 2);

  // converts / weight transposes
  conv_bf16<<<8192, 256, 0, stream>>>(x, x_bf, 2097152);
  conv_bf16<<<1024, 256, 0, stream>>>(Wdkv, wdkv, 262144);
  conv_bf16<<<4096, 256, 0, stream>>>(Wo, wo, 1048576);
  transpose_f32_bf16<<<4096, 256, 0, stream>>>(Wuk, wukT, 2048, 512);
  transpose_f32_bf16<<<4096, 256, 0, stream>>>(Wdq, wdqT, 512, 2048);
  transpose_f32_bf16<<<4096, 256, 0, stream>>>(Wuv, wuvT, 2048, 512);

  // M1 = W_uk^T W_uk  (bf16 out; exactly symmetric by construction)
  gemm_nt<<<dim3(4, 4, 1), 256, 0, stream>>>(wukT, wukT, nullptr, m1,
      512, 512, 2048, 2048, 2048, 512, 0, 0, 0, 0, 1);
  // k_abs = W_dq^T @ M1  (uses M1 symmetry for the NT form)
  gemm_nt<<<dim3(16, 4, 1), 256, 0, stream>>>(wdqT, m1, nullptr, kabs,
      2048, 512, 512, 512, 512, 512, 0, 0, 0, 0, 1);
  // v_flat = W_uv^T @ W_o^T
  gemm_nt<<<dim3(4, 16, 1), 256, 0, stream>>>(wuvT, wo, nullptr, vflat,
      512, 2048, 2048, 2048, 2048, 2048, 0, 0, 0, 0, 1);
  // c_kv = x @ W_dkv^T  -> fp32 output chunk 2 + bf16 copy
  gemm_nt<<<dim3(32, 4, 1), 256, 0, stream>>>(x_bf, wdkv, ckv_f, ckvb,
      4096, 512, 2048, 2048, 2048, 512, 0, 0, 0, 0, 1);

  trans_kabs<<<4096, 256, 0, stream>>>(kabs, kabsT);
  trans_vabs<<<4096, 256, 0, stream>>>(vflat, vabsT);
  trans_ckvT<<<dim3(32, 8, 2), 256, 0, stream>>>(ckvb, ckvT);

  // fused q_lat + causal flash attention (latent K=V), balanced qtile pairs
  flash_mhla<<<dim3(8, 16, 2), 512, 0, stream>>>(x_bf, kabsT, ckvb, ckvT, outlat);

  // y[b][t][h*128+d] = out_lat[b][h][t][:] @ v_abs[h]
  gemm_nt<<<dim3(16, 1, 32), 256, 0, stream>>>(outlat, vabsT, y, nullptr,
      2048, 128, 512, 512, 512, 2048,
      (long)2048 * 512, (long)128 * 512, (long)2048 * 2048, 128L, 16);
}